// Round 2
// baseline (252.175 us; speedup 1.0000x reference)
//
#include <hip/hip_runtime.h>

// Splice: out[m][j] = a[m/R][j]      for j <  sa
//                   = b[m][j - sa]   for sa <= j < sa+sb
//                   = dst[m][j]      for j >= sa+sb
// sa = seq_len_a[m/R], sb = seq_len_b[m].
//
// One block per row: seq loads amortized over the whole row, unroll-4 for
// 4 independent int4 loads in flight. Nontemporal on stream-once data
// (out stores, dst tail loads) to keep L2 free for a-row x4 reuse.

typedef int v4i __attribute__((ext_vector_type(4)));

__device__ __forceinline__ v4i splice_vec(
    int vc, int sa, int total, int nA, int nTail,
    const int* __restrict__ a_row, const int* __restrict__ b_row,
    const int* __restrict__ dst_row)
{
    const int j0 = vc << 2;
    if (vc < nA) {
        // fully inside A (aligned: j0 % 4 == 0)
        return *(const v4i*)(a_row + j0);
    } else if (vc >= nTail) {
        // fully inside pass-through tail; read-once -> nontemporal
        return __builtin_nontemporal_load((const v4i*)(dst_row + j0));
    } else {
        // mixed / B window: at most ~(sb/4 + 2) vec4s per row
        v4i v;
#pragma unroll
        for (int t = 0; t < 4; ++t) {
            const int j = j0 + t;
            v[t] = (j < sa) ? a_row[j] : ((j < total) ? b_row[j - sa] : dst_row[j]);
        }
        return v;
    }
}

__global__ __launch_bounds__(256) void splice_kernel(
    const int* __restrict__ dst,
    const int* __restrict__ a,
    const int* __restrict__ b,
    const int* __restrict__ seq_a,
    const int* __restrict__ seq_b,
    int* __restrict__ out,
    int LEN_OUT, int LEN_A, int LEN_B, int repeat_shift)
{
    const int m   = blockIdx.x;
    const int tid = threadIdx.x;

    const int ia    = m >> repeat_shift;
    const int sa    = seq_a[ia];          // block-uniform -> scalar load
    const int sb    = seq_b[m];           // block-uniform -> scalar load
    const int total = sa + sb;
    const int nvec  = LEN_OUT >> 2;       // 4128
    const int nA    = sa >> 2;            // vc <  nA    -> fully in A
    const int nTail = (total + 3) >> 2;   // vc >= nTail -> fully in tail

    const int* a_row   = a   + (size_t)ia * LEN_A;
    const int* b_row   = b   + (size_t)m  * LEN_B;
    const int* dst_row = dst + (size_t)m  * LEN_OUT;
    int*       out_row = out + (size_t)m  * LEN_OUT;

    const int full = nvec >> 8;           // 16 full 256-wide sweeps
#pragma unroll 4
    for (int k = 0; k < full; ++k) {
        const int vc = (k << 8) + tid;
        v4i v = splice_vec(vc, sa, total, nA, nTail, a_row, b_row, dst_row);
        __builtin_nontemporal_store(v, (v4i*)(out_row + (vc << 2)));
    }
    // remainder (nvec % 256 = 32 vec4s)
    const int vc = (full << 8) + tid;
    if (vc < nvec) {
        v4i v = splice_vec(vc, sa, total, nA, nTail, a_row, b_row, dst_row);
        __builtin_nontemporal_store(v, (v4i*)(out_row + (vc << 2)));
    }
}

extern "C" void kernel_launch(void* const* d_in, const int* in_sizes, int n_in,
                              void* d_out, int out_size, void* d_ws, size_t ws_size,
                              hipStream_t stream) {
    const int* dst   = (const int*)d_in[0];  // (M, LEN_OUT)
    const int* a     = (const int*)d_in[1];  // (BS, LEN_A)
    const int* b     = (const int*)d_in[2];  // (M, LEN_B)
    const int* seq_a = (const int*)d_in[3];  // (BS,)
    const int* seq_b = (const int*)d_in[4];  // (M,)
    int* out = (int*)d_out;

    const int BS      = in_sizes[3];
    const int M       = in_sizes[4];
    const int LEN_A   = in_sizes[1] / BS;
    const int LEN_B   = in_sizes[2] / M;
    const int LEN_OUT = in_sizes[0] / M;
    const int repeat  = M / BS;              // 4
    int repeat_shift = 0;
    while ((1 << repeat_shift) < repeat) ++repeat_shift;

    splice_kernel<<<dim3(M), dim3(256), 0, stream>>>(dst, a, b, seq_a, seq_b, out,
                                                     LEN_OUT, LEN_A, LEN_B, repeat_shift);
}

// Round 3
// 248.821 us; speedup vs baseline: 1.0135x; 1.0135x over previous
//
#include <hip/hip_runtime.h>

// Splice: out[m][j] = a[m/4][j]      for j <  sa
//                   = b[m][j - sa]   for sa <= j < sa+sb
//                   = dst[m][j]      for j >= sa+sb
// sa = seq_len_a[m/4], sb = seq_len_b[m].
//
// One block per a-row (ia): the 4 repeat rows m = 4*ia+r are fused, so each
// A-region vec4 is loaded ONCE and stored to 4 rows (VMEM loads cut 4x on
// ~half the elements), and sa/nA are block-uniform for all rows.
// 512 blocks x 1024 threads = 2 blocks/CU = 32 waves/CU (full occupancy).

typedef int v4i __attribute__((ext_vector_type(4)));

__global__ __launch_bounds__(1024) void splice4_kernel(
    const int* __restrict__ dst,
    const int* __restrict__ a,
    const int* __restrict__ b,
    const int* __restrict__ seq_a,
    const int* __restrict__ seq_b,
    int* __restrict__ out,
    int LEN_OUT, int LEN_A, int LEN_B)
{
    const int ia  = blockIdx.x;
    const int tid = threadIdx.x;
    const int m0  = ia << 2;

    const int sa   = seq_a[ia];         // block-uniform
    const int nA   = sa >> 2;           // vc < nA -> fully in A for ALL 4 rows
    const int nvec = LEN_OUT >> 2;      // 4128

    int sb[4], total[4], nTail[4];
    const int *b_row[4], *dst_row[4];
    int *out_row[4];
#pragma unroll
    for (int r = 0; r < 4; ++r) {
        const int m = m0 + r;
        sb[r]    = seq_b[m];            // block-uniform
        total[r] = sa + sb[r];
        nTail[r] = (total[r] + 3) >> 2; // vc >= nTail -> fully pass-through
        b_row[r]   = b   + (size_t)m * LEN_B;
        dst_row[r] = dst + (size_t)m * LEN_OUT;
        out_row[r] = out + (size_t)m * LEN_OUT;
    }
    const int* a_row = a + (size_t)ia * LEN_A;

    for (int vc = tid; vc < nvec; vc += 1024) {
        const int j0 = vc << 2;
        if (vc < nA) {
            // A region: one load, four stores
            const v4i va = *(const v4i*)(a_row + j0);
#pragma unroll
            for (int r = 0; r < 4; ++r)
                __builtin_nontemporal_store(va, (v4i*)(out_row[r] + j0));
        } else {
#pragma unroll
            for (int r = 0; r < 4; ++r) {
                v4i v;
                if (vc >= nTail[r]) {
                    v = __builtin_nontemporal_load((const v4i*)(dst_row[r] + j0));
                } else {
                    // mixed / B window: <= ~34 vec4s per row
#pragma unroll
                    for (int t = 0; t < 4; ++t) {
                        const int j = j0 + t;
                        v[t] = (j < sa) ? a_row[j]
                             : ((j < total[r]) ? b_row[r][j - sa] : dst_row[r][j]);
                    }
                }
                __builtin_nontemporal_store(v, (v4i*)(out_row[r] + j0));
            }
        }
    }
}

extern "C" void kernel_launch(void* const* d_in, const int* in_sizes, int n_in,
                              void* d_out, int out_size, void* d_ws, size_t ws_size,
                              hipStream_t stream) {
    const int* dst   = (const int*)d_in[0];  // (M, LEN_OUT)
    const int* a     = (const int*)d_in[1];  // (BS, LEN_A)
    const int* b     = (const int*)d_in[2];  // (M, LEN_B)
    const int* seq_a = (const int*)d_in[3];  // (BS,)
    const int* seq_b = (const int*)d_in[4];  // (M,)
    int* out = (int*)d_out;

    const int BS      = in_sizes[3];
    const int M       = in_sizes[4];
    const int LEN_A   = in_sizes[1] / BS;
    const int LEN_B   = in_sizes[2] / M;
    const int LEN_OUT = in_sizes[0] / M;

    splice4_kernel<<<dim3(BS), dim3(1024), 0, stream>>>(dst, a, b, seq_a, seq_b, out,
                                                        LEN_OUT, LEN_A, LEN_B);
}